// Round 8
// baseline (278.556 us; speedup 1.0000x reference)
//
#include <hip/hip_runtime.h>
#include <stdint.h>

#define B_ROWS 8192
#define I_DIM  1024
#define N_DIM  1024
#define NDEG   9                  // D+1 (d = 0..8)
#define K_DIM  (I_DIM * (NDEG-1)) // 8192; k = i*8 + (d-1), d = 1..8 (d=0 folded into bias)

#define BM 128
#define BN 128
#define BK 64
#define NT (K_DIM / BK)           // 128 K-tiles; tile kt covers i in [kt*8, kt*8+8)

typedef __attribute__((ext_vector_type(8)))  short short8;
typedef __attribute__((ext_vector_type(16))) float f32x16;

__device__ __forceinline__ unsigned short f2bf(float f) {
  union { float f; uint32_t u; } v; v.f = f;
  uint32_t u = v.u;
  u += 0x7FFFu + ((u >> 16) & 1u);   // round-to-nearest-even
  return (unsigned short)(u >> 16);
}

__device__ __forceinline__ float bf2f(unsigned short h) {
  union { uint32_t u; float f; } v; v.u = ((uint32_t)h) << 16;
  return v.f;
}

// packed f32->bf16 (RTNE), 1 instr for 2 values; no builtin on gfx950, asm only
__device__ __forceinline__ uint32_t pk_bf16(float lo, float hi) {
  uint32_t r;
  asm("v_cvt_pk_bf16_f32 %0, %1, %2" : "=v"(r) : "v"(lo), "v"(hi));
  return r;
}

// fast tanh: 1 - 2/(e^{2x}+1); exact limits at +-inf, err ~1e-7 << bf16 quantization
__device__ __forceinline__ float fast_tanh(float x) {
  float e = __expf(2.0f * x);
  return 1.0f - __fdividef(2.0f, e + 1.0f);
}

__device__ __forceinline__ int h2(int r) { return (r >> 2) & 7; }

// ---------------- repack: C[i,o,d] fp32 -> Bt[o, i*8+(d-1)] bf16 (d>=1); bias[o] += sum_i C[i,o,0]
__global__ __launch_bounds__(256) void repack_kernel(const float* __restrict__ cf,
                                                     unsigned short* __restrict__ Bt,
                                                     float* __restrict__ bias) {
  __shared__ unsigned short L[32][584];   // [i_local][o_local*9+d], padded
  const int i0  = blockIdx.x * 32;
  const int o0  = blockIdx.y * 64;
  const int tid = threadIdx.x;

  #pragma unroll
  for (int j = 0; j < 18; ++j) {               // 18*256 = 4608 float4 = 32*576 floats
    const int f4  = j * 256 + tid;
    const int il  = f4 / 144;
    const int odq = f4 % 144;
    const float4 v = *reinterpret_cast<const float4*>(
        cf + ((size_t)(i0 + il) * N_DIM + o0) * NDEG + (size_t)odq * 4);
    ushort4 w;
    w.x = f2bf(v.x); w.y = f2bf(v.y); w.z = f2bf(v.z); w.w = f2bf(v.w);
    *reinterpret_cast<ushort4*>(&L[il][odq * 4]) = w;
  }
  __syncthreads();

  // one (o, i-octet) unit per thread: 64 consecutive shorts = 8 i x 8 d
  const int o  = tid >> 2;        // 0..63
  const int ci = tid & 3;         // 0..3
  const size_t base = (size_t)(o0 + o) * K_DIM + (size_t)(i0 + ci * 8) * 8;
  #pragma unroll
  for (int p = 0; p < 8; ++p) {   // i = i0 + ci*8 + p; shorts [d-1 = 0..7]
    const int il = ci * 8 + p;
    uint4 u;
    u.x = (uint32_t)L[il][o*9 + 1] | ((uint32_t)L[il][o*9 + 2] << 16);
    u.y = (uint32_t)L[il][o*9 + 3] | ((uint32_t)L[il][o*9 + 4] << 16);
    u.z = (uint32_t)L[il][o*9 + 5] | ((uint32_t)L[il][o*9 + 6] << 16);
    u.w = (uint32_t)L[il][o*9 + 7] | ((uint32_t)L[il][o*9 + 8] << 16);
    *reinterpret_cast<uint4*>(Bt + base + (size_t)p * 8) = u;
  }
  if (tid < 64) {
    float s = 0.f;
    #pragma unroll
    for (int il = 0; il < 32; ++il) s += bf2f(L[il][tid * 9]);
    atomicAdd(&bias[o0 + tid], s);
  }
}

// ---------------- fused basis+GEMM: C[m,n] = bias[n] + sum_k T(x)[m,k]*Bt[n,k] ------------
// R7 showed LDS (~2050cy) + VALU (~1370cy) per tile ADD instead of overlapping: with all
// waves of the CU in ONE block, every tile-boundary barrier drains the whole CU. This
// version: 128x128 tile, 256 threads (4 waves, 2x2, 64x64/wave), 64 KB LDS -> TWO
// INDEPENDENTLY BARRIERED blocks per CU. Per-CU pipe totals are unchanged; when one
// block drains, the other's waves keep LDS/MFMA busy. XCD partition: nt = bid&7 ->
// each XCD's L2 owns one 2 MB B-slab; x re-reads hit LLC.
__global__ __launch_bounds__(256, 2) void gemm_kernel(const float* __restrict__ x,
                                                      const unsigned short* __restrict__ Bt,
                                                      const float* __restrict__ bias,
                                                      float* __restrict__ C) {
  extern __shared__ unsigned short sm[];   // As: [2][8192] @0 ; Bs: [2][8192] @16384
  const int tid  = threadIdx.x;
  const int lane = tid & 63;
  const int wave = tid >> 6;        // 0..3
  const int l31  = lane & 31;
  const int half = lane >> 5;       // 0..1 -> k-offset 8*half
  const int wm   = wave >> 1;       // 0..1
  const int wn   = wave & 1;        // 0..1

  // XCD partition: nt = bid&7 (8 n-slabs -> 8 XCDs), mt = bid>>3 (0..63)
  const int bid = blockIdx.x;
  const int nt  = bid & 7;
  const int mt  = bid >> 3;
  const int m0  = mt * BM;
  const int n0  = nt * BN;

  const int sr   = tid >> 3;        // 0..31: staging row / basis row-quarter
  const int slot = tid & 7;         // 16B chunk slot (staging) / basis i_loc

  const unsigned short* Bbase = Bt + (size_t)n0 * K_DIM;

  // hoisted basis constants: LDS write offsets (shorts, within an A-buffer) + x pointers
  int awoff[4];
  const float* xptr[4];
  #pragma unroll
  for (int q = 0; q < 4; ++q) {
    const int r_ = q * 32 + sr;
    awoff[q] = r_ * 64 + (slot ^ h2(r_)) * 8;
    xptr[q]  = x + (size_t)(m0 + r_) * I_DIM + slot;
  }

  f32x16 acc[2][2];
  #pragma unroll
  for (int a = 0; a < 2; ++a)
    #pragma unroll
    for (int b = 0; b < 2; ++b)
      #pragma unroll
      for (int r = 0; r < 16; ++r)
        acc[a][b][r] = 0.f;

#define STAGE_B(s, bf, kk) { const int r_ = (s)*32 + sr; const int gc_ = slot ^ h2(r_);     \
    __builtin_amdgcn_global_load_lds(                                                       \
        (const __attribute__((address_space(1))) void*)(Bbase + (size_t)r_*K_DIM + (kk) + gc_*8), \
        (__attribute__((address_space(3))) void*)&sm[16384 + (bf)*8192 + r_*64 + slot*8], 16, 0, 0); }
#define STAGE_B4(bf, kk) { STAGE_B(0, bf, kk) STAGE_B(1, bf, kk) STAGE_B(2, bf, kk) STAGE_B(3, bf, kk) }

#define LOADX(xr, tt) {                                                                     \
    _Pragma("unroll")                                                                       \
    for (int q = 0; q < 4; ++q) xr[q] = xptr[q][(tt) * 8]; }

// one basis quarter: row q*32+sr, value = T_1..T_8(clamp(tanh(xv))) -> 16B LDS write
#define BASIS_Q(bf, q, xv) {                                                                \
      float t = fast_tanh(xv);                                                              \
      t = fminf(fmaxf(t, -0.999f), 0.999f);                                                 \
      const float t2 = t + t;                                                               \
      const float T1 = t;                                                                   \
      const float T2 = t2*t - 1.0f;                                                         \
      const float T3 = t2*T2 - T1;                                                          \
      const float T4 = t2*T3 - T2;                                                          \
      const float T5 = t2*T4 - T3;                                                          \
      const float T6 = t2*T5 - T4;                                                          \
      const float T7 = t2*T6 - T5;                                                          \
      const float T8 = t2*T7 - T6;                                                          \
      uint4 u;                                                                              \
      u.x = pk_bf16(T1, T2); u.y = pk_bf16(T3, T4);                                         \
      u.z = pk_bf16(T5, T6); u.w = pk_bf16(T7, T8);                                         \
      *reinterpret_cast<uint4*>(&sm[(bf)*8192 + awoff[q]]) = u; }

  const int rowA0 = wm * 64 + l31;
  const int rowA1 = wm * 64 + 32 + l31;
  const int rowB0 = wn * 64 + l31;
  const int rowB1 = wn * 64 + 32 + l31;
  const int hA0 = h2(rowA0), hA1 = h2(rowA1), hB0 = h2(rowB0), hB1 = h2(rowB1);

#define READ4(Asc, Bsc, av, bv, ks) {                                                        \
    const int c_ = (ks) * 2 + half;                                                          \
    av[0][ks] = *reinterpret_cast<const short8*>(&Asc[rowA0 * 64 + (c_ ^ hA0) * 8]);         \
    av[1][ks] = *reinterpret_cast<const short8*>(&Asc[rowA1 * 64 + (c_ ^ hA1) * 8]);         \
    bv[0][ks] = *reinterpret_cast<const short8*>(&Bsc[rowB0 * 64 + (c_ ^ hB0) * 8]);         \
    bv[1][ks] = *reinterpret_cast<const short8*>(&Bsc[rowB1 * 64 + (c_ ^ hB1) * 8]); }

#define MFMA4(av, bv, ks)                                                                    \
    acc[0][0] = __builtin_amdgcn_mfma_f32_32x32x16_bf16(av[0][ks], bv[0][ks], acc[0][0], 0, 0, 0); \
    acc[0][1] = __builtin_amdgcn_mfma_f32_32x32x16_bf16(av[0][ks], bv[1][ks], acc[0][1], 0, 0, 0); \
    acc[1][0] = __builtin_amdgcn_mfma_f32_32x32x16_bf16(av[1][ks], bv[0][ks], acc[1][0], 0, 0, 0); \
    acc[1][1] = __builtin_amdgcn_mfma_f32_32x32x16_bf16(av[1][ks], bv[1][ks], acc[1][1], 0, 0, 0);

// full tile: stage B for kt+1, optionally prefetch x for kt+2, interleaved
// [reads | basis-quarter(kt+1) | MFMA] per ks, counted-vmcnt barrier.
#define TILE_FULL(kt_, XC, XL, LOADEN) {                                                     \
    const int cur_ = (kt_) & 1; const int nxt_ = cur_ ^ 1;                                   \
    const unsigned short* Asc = &sm[cur_ * 8192];                                            \
    const unsigned short* Bsc = &sm[16384 + cur_ * 8192];                                    \
    STAGE_B4(nxt_, ((kt_) + 1) * BK)                                                         \
    if (LOADEN) { LOADX(XL, (kt_) + 2) }                                                     \
    __builtin_amdgcn_sched_barrier(0);                                                       \
    short8 av[2][4], bv[2][4];                                                               \
    READ4(Asc, Bsc, av, bv, 0)                                                               \
    READ4(Asc, Bsc, av, bv, 1)                                                               \
    BASIS_Q(nxt_, 0, XC[0])                                                                  \
    MFMA4(av, bv, 0)                                                                         \
    __builtin_amdgcn_sched_group_barrier(0x100, 8, 0);                                       \
    __builtin_amdgcn_sched_group_barrier(0x200, 1, 0);                                       \
    __builtin_amdgcn_sched_group_barrier(0x008, 4, 0);                                       \
    READ4(Asc, Bsc, av, bv, 2)                                                               \
    BASIS_Q(nxt_, 1, XC[1])                                                                  \
    MFMA4(av, bv, 1)                                                                         \
    __builtin_amdgcn_sched_group_barrier(0x100, 4, 0);                                       \
    __builtin_amdgcn_sched_group_barrier(0x200, 1, 0);                                       \
    __builtin_amdgcn_sched_group_barrier(0x008, 4, 0);                                       \
    READ4(Asc, Bsc, av, bv, 3)                                                               \
    BASIS_Q(nxt_, 2, XC[2])                                                                  \
    MFMA4(av, bv, 2)                                                                         \
    __builtin_amdgcn_sched_group_barrier(0x100, 4, 0);                                       \
    __builtin_amdgcn_sched_group_barrier(0x200, 1, 0);                                       \
    __builtin_amdgcn_sched_group_barrier(0x008, 4, 0);                                       \
    BASIS_Q(nxt_, 3, XC[3])                                                                  \
    MFMA4(av, bv, 3)                                                                         \
    __builtin_amdgcn_sched_group_barrier(0x200, 1, 0);                                       \
    __builtin_amdgcn_sched_group_barrier(0x008, 4, 0);                                       \
    __builtin_amdgcn_sched_barrier(0);                                                       \
    if (LOADEN) asm volatile("s_waitcnt vmcnt(4) lgkmcnt(0)" ::: "memory");                  \
    else        asm volatile("s_waitcnt vmcnt(0) lgkmcnt(0)" ::: "memory");                  \
    __builtin_amdgcn_s_barrier();                                                            \
    __builtin_amdgcn_sched_barrier(0); }

  // prologue: stage B tile0, x for tiles 0 and 1; basis tile0 -> buf0
  float xrA[4], xrB[4];
  STAGE_B4(0, 0)
  LOADX(xrA, 0)
  LOADX(xrB, 1)
  asm volatile("s_waitcnt vmcnt(4)" ::: "memory");   // B stages + xrA done; xrB in flight
  BASIS_Q(0, 0, xrA[0]) BASIS_Q(0, 1, xrA[1]) BASIS_Q(0, 2, xrA[2]) BASIS_Q(0, 3, xrA[3])
  asm volatile("s_waitcnt lgkmcnt(0)" ::: "memory");
  __builtin_amdgcn_s_barrier();
  __builtin_amdgcn_sched_barrier(0);

  // main loop: tiles 0..125 (basis+load), tile 126 (basis, no load), tile 127 (compute only)
  for (int kt = 0; kt < 126; kt += 2) {
    TILE_FULL(kt,     xrB, xrA, 1)     // even: consume xrB (x of kt+1), load xrA (x of kt+2)
    TILE_FULL(kt + 1, xrA, xrB, 1)     // odd : consume xrA,            load xrB
  }
  TILE_FULL(126, xrB, xrA, 0)          // basis for t127 from xrB; nothing left to load

  { // tile 127: compute only
    const unsigned short* Asc = &sm[1 * 8192];
    const unsigned short* Bsc = &sm[16384 + 1 * 8192];
    short8 av[2][4], bv[2][4];
    READ4(Asc, Bsc, av, bv, 0)
    #pragma unroll
    for (int ks = 0; ks < 4; ++ks) {
      if (ks < 3) READ4(Asc, Bsc, av, bv, ks + 1)
      MFMA4(av, bv, ks)
      if (ks < 3) __builtin_amdgcn_sched_group_barrier(0x100, 4, 0);
      __builtin_amdgcn_sched_group_barrier(0x008, 4, 0);
    }
  }
#undef TILE_FULL
#undef MFMA4
#undef READ4
#undef BASIS_Q
#undef LOADX
#undef STAGE_B4
#undef STAGE_B

  // epilogue: 32x32 C/D layout col = lane&31, row = (reg&3) + 8*(reg>>2) + 4*(lane>>5)
  #pragma unroll
  for (int ni = 0; ni < 2; ++ni) {
    const int col  = n0 + wn * 64 + ni * 32 + l31;
    const float bc = bias[col];
    #pragma unroll
    for (int mi = 0; mi < 2; ++mi) {
      const int rbase = m0 + wm * 64 + mi * 32 + 4 * half;
      #pragma unroll
      for (int r = 0; r < 16; ++r) {
        const int row = rbase + (r & 3) + 8 * (r >> 2);
        C[(size_t)row * N_DIM + col] = acc[mi][ni][r] + bc;
      }
    }
  }
}

extern "C" void kernel_launch(void* const* d_in, const int* in_sizes, int n_in,
                              void* d_out, int out_size, void* d_ws, size_t ws_size,
                              hipStream_t stream) {
  const float* x      = (const float*)d_in[0];
  const float* coeffs = (const float*)d_in[1];
  float* y            = (float*)d_out;

  const size_t bt_bytes = (size_t)N_DIM * K_DIM * sizeof(unsigned short); // 16.78 MB
  unsigned short* Bt = (unsigned short*)d_ws;
  float* bias        = (float*)((char*)d_ws + bt_bytes);

  // bias accumulator must start at zero (ws is poisoned 0xAA each call)
  hipMemsetAsync(bias, 0, N_DIM * sizeof(float), stream);

  // 64 KB dynamic LDS (double-buffered A+B); 2 blocks/CU
  hipFuncSetAttribute((const void*)gemm_kernel,
                      hipFuncAttributeMaxDynamicSharedMemorySize, 65536);

  repack_kernel<<<dim3(I_DIM / 32, N_DIM / 64), 256, 0, stream>>>(coeffs, Bt, bias);
  gemm_kernel<<<(B_ROWS / BM) * (N_DIM / BN), 256, 65536, stream>>>(x, Bt, bias, y);
}

// Round 9
// 274.882 us; speedup vs baseline: 1.0134x; 1.0134x over previous
//
#include <hip/hip_runtime.h>
#include <stdint.h>

#define B_ROWS 8192
#define I_DIM  1024
#define N_DIM  1024
#define NDEG   9                  // D+1 (d = 0..8)
#define K_DIM  (I_DIM * (NDEG-1)) // 8192; k = i*8 + (d-1), d = 1..8 (d=0 folded into bias)

#define BM 256
#define BN 128
#define BK 64
#define NT (K_DIM / BK)           // 128 K-tiles; tile kt covers i in [kt*8, kt*8+8)

typedef __attribute__((ext_vector_type(8)))  short short8;
typedef __attribute__((ext_vector_type(16))) float f32x16;

__device__ __forceinline__ unsigned short f2bf(float f) {
  union { float f; uint32_t u; } v; v.f = f;
  uint32_t u = v.u;
  u += 0x7FFFu + ((u >> 16) & 1u);   // round-to-nearest-even
  return (unsigned short)(u >> 16);
}

__device__ __forceinline__ float bf2f(unsigned short h) {
  union { uint32_t u; float f; } v; v.u = ((uint32_t)h) << 16;
  return v.f;
}

// packed f32->bf16 (RTNE), 1 instr for 2 values; no builtin on gfx950, asm only
__device__ __forceinline__ uint32_t pk_bf16(float lo, float hi) {
  uint32_t r;
  asm("v_cvt_pk_bf16_f32 %0, %1, %2" : "=v"(r) : "v"(lo), "v"(hi));
  return r;
}

// fast tanh: 1 - 2/(e^{2x}+1); exact limits at +-inf, err ~1e-7 << bf16 quantization
__device__ __forceinline__ float fast_tanh(float x) {
  float e = __expf(2.0f * x);
  return 1.0f - __fdividef(2.0f, e + 1.0f);
}

__device__ __forceinline__ int h2(int r) { return (r >> 2) & 7; }

// ---------------- repack: C[i,o,d] fp32 -> Bt[o, i*8+(d-1)] bf16 (d>=1); bias[o] += sum_i C[i,o,0]
__global__ __launch_bounds__(256) void repack_kernel(const float* __restrict__ cf,
                                                     unsigned short* __restrict__ Bt,
                                                     float* __restrict__ bias) {
  __shared__ unsigned short L[32][584];   // [i_local][o_local*9+d], padded
  const int i0  = blockIdx.x * 32;
  const int o0  = blockIdx.y * 64;
  const int tid = threadIdx.x;

  #pragma unroll
  for (int j = 0; j < 18; ++j) {               // 18*256 = 4608 float4 = 32*576 floats
    const int f4  = j * 256 + tid;
    const int il  = f4 / 144;
    const int odq = f4 % 144;
    const float4 v = *reinterpret_cast<const float4*>(
        cf + ((size_t)(i0 + il) * N_DIM + o0) * NDEG + (size_t)odq * 4);
    ushort4 w;
    w.x = f2bf(v.x); w.y = f2bf(v.y); w.z = f2bf(v.z); w.w = f2bf(v.w);
    *reinterpret_cast<ushort4*>(&L[il][odq * 4]) = w;
  }
  __syncthreads();

  // one (o, i-octet) unit per thread: 64 consecutive shorts = 8 i x 8 d
  const int o  = tid >> 2;        // 0..63
  const int ci = tid & 3;         // 0..3
  const size_t base = (size_t)(o0 + o) * K_DIM + (size_t)(i0 + ci * 8) * 8;
  #pragma unroll
  for (int p = 0; p < 8; ++p) {   // i = i0 + ci*8 + p; shorts [d-1 = 0..7]
    const int il = ci * 8 + p;
    uint4 u;
    u.x = (uint32_t)L[il][o*9 + 1] | ((uint32_t)L[il][o*9 + 2] << 16);
    u.y = (uint32_t)L[il][o*9 + 3] | ((uint32_t)L[il][o*9 + 4] << 16);
    u.z = (uint32_t)L[il][o*9 + 5] | ((uint32_t)L[il][o*9 + 6] << 16);
    u.w = (uint32_t)L[il][o*9 + 7] | ((uint32_t)L[il][o*9 + 8] << 16);
    *reinterpret_cast<uint4*>(Bt + base + (size_t)p * 8) = u;
  }
  if (tid < 64) {
    float s = 0.f;
    #pragma unroll
    for (int il = 0; il < 32; ++il) s += bf2f(L[il][tid * 9]);
    atomicAdd(&bias[o0 + tid], s);
  }
}

// ---------------- fused basis+GEMM, 2-deep register pipeline over triple-buffered LDS ----
// R7/R8 showed no pipe saturated yet slot invariant ~3490cy -> wall = per-wave dependency
// chain (MFMA waits on same-tile ds_reads, ~150cy x4 + full drain). This version:
// TRIPLE-buffered A(3x32K)+B(3x16K) = 144 KB, 8 waves (4Mx2N). Tile kt consumes fragment
// REGISTERS read during tile kt-1 (zero lgkm dep on critical path); reads(kt+1), basis(kt+2)
// (fused Chebyshev, x 4-deep prefetch) and B-DMA(kt+2) all proceed under the MFMA cluster;
// ONE counted barrier per tile (vmcnt(4) keeps x in flight). R7 XCD swizzle restored
// (R8's nt=bid&7 broke x locality: FETCH 82->144 MB).
__global__ __launch_bounds__(512, 2) void gemm_kernel(const float* __restrict__ x,
                                                      const unsigned short* __restrict__ Bt,
                                                      const float* __restrict__ bias,
                                                      float* __restrict__ C) {
  extern __shared__ unsigned short sm[];   // A: 3x16384 shorts @0 ; B: 3x8192 @49152
  const int tid  = threadIdx.x;
  const int lane = tid & 63;
  const int wave = tid >> 6;        // 0..7
  const int l31  = lane & 31;
  const int half = lane >> 5;       // 0..1 -> k-offset 8*half
  const int wm   = wave >> 1;       // 0..3
  const int wn   = wave & 1;        // 0..1

  // bijective XCD swizzle: all 8 n-blocks of one m-tile share bid%8 -> same XCD L2 (x reuse)
  const int bid = blockIdx.x;
  const int mt  = (bid & 7) + 8 * (bid >> 6);
  const int nt  = (bid >> 3) & 7;
  const int m0  = mt * BM;
  const int n0  = nt * BN;

  const int sr   = tid >> 3;        // 0..63: staging row / basis row-quarter
  const int slot = tid & 7;         // 16B chunk slot (staging) / basis i_loc

  const unsigned short* Bbase = Bt + (size_t)n0 * K_DIM;

  // hoisted basis constants: LDS write offsets (shorts, within an A-buffer) + x pointers
  int awoff[4];
  const float* xptr[4];
  #pragma unroll
  for (int q = 0; q < 4; ++q) {
    const int r_ = q * 64 + sr;
    awoff[q] = r_ * 64 + (slot ^ h2(r_)) * 8;
    xptr[q]  = x + (size_t)(m0 + r_) * I_DIM + slot;
  }

  f32x16 acc[2][2];
  #pragma unroll
  for (int a = 0; a < 2; ++a)
    #pragma unroll
    for (int b = 0; b < 2; ++b)
      #pragma unroll
      for (int r = 0; r < 16; ++r)
        acc[a][b][r] = 0.f;

#define STAGE_B2(bf, kk) {                                                                  \
    _Pragma("unroll")                                                                       \
    for (int s_ = 0; s_ < 2; ++s_) {                                                        \
      const int r_ = s_ * 64 + sr; const int gc_ = slot ^ h2(r_);                           \
      __builtin_amdgcn_global_load_lds(                                                     \
        (const __attribute__((address_space(1))) void*)(Bbase + (size_t)r_*K_DIM + (kk) + gc_*8), \
        (__attribute__((address_space(3))) void*)&sm[49152 + (bf)*8192 + r_*64 + slot*8], 16, 0, 0); \
    } }

#define LOADX(xr, tt) {                                                                     \
    _Pragma("unroll")                                                                       \
    for (int q = 0; q < 4; ++q) xr[q] = xptr[q][(tt) * 8]; }

// one basis quarter: row q*64+sr, value = T_1..T_8(clamp(tanh(xv))) -> 16B LDS write
#define BASIS_Q(bf, q, xv) {                                                                \
      float t = fast_tanh(xv);                                                              \
      t = fminf(fmaxf(t, -0.999f), 0.999f);                                                 \
      const float t2 = t + t;                                                               \
      const float T1 = t;                                                                   \
      const float T2 = t2*t - 1.0f;                                                         \
      const float T3 = t2*T2 - T1;                                                          \
      const float T4 = t2*T3 - T2;                                                          \
      const float T5 = t2*T4 - T3;                                                          \
      const float T6 = t2*T5 - T4;                                                          \
      const float T7 = t2*T6 - T5;                                                          \
      const float T8 = t2*T7 - T6;                                                          \
      uint4 u;                                                                              \
      u.x = pk_bf16(T1, T2); u.y = pk_bf16(T3, T4);                                         \
      u.z = pk_bf16(T5, T6); u.w = pk_bf16(T7, T8);                                         \
      *reinterpret_cast<uint4*>(&sm[(bf)*16384 + awoff[q]]) = u; }

  const int rowA0 = wm * 64 + l31;
  const int rowA1 = wm * 64 + 32 + l31;
  const int rowB0 = wn * 64 + l31;
  const int rowB1 = wn * 64 + 32 + l31;
  const int hA0 = h2(rowA0), hA1 = h2(rowA1), hB0 = h2(rowB0), hB1 = h2(rowB1);

#define READ4(Ar, Br, av, bv, ks) {                                                          \
    const int c_ = (ks) * 2 + half;                                                          \
    av[0][ks] = *reinterpret_cast<const short8*>(&(Ar)[rowA0 * 64 + (c_ ^ hA0) * 8]);        \
    av[1][ks] = *reinterpret_cast<const short8*>(&(Ar)[rowA1 * 64 + (c_ ^ hA1) * 8]);        \
    bv[0][ks] = *reinterpret_cast<const short8*>(&(Br)[rowB0 * 64 + (c_ ^ hB0) * 8]);        \
    bv[1][ks] = *reinterpret_cast<const short8*>(&(Br)[rowB1 * 64 + (c_ ^ hB1) * 8]); }

#define MFMA4(av, bv, ks)                                                                    \
    acc[0][0] = __builtin_amdgcn_mfma_f32_32x32x16_bf16(av[0][ks], bv[0][ks], acc[0][0], 0, 0, 0); \
    acc[0][1] = __builtin_amdgcn_mfma_f32_32x32x16_bf16(av[0][ks], bv[1][ks], acc[0][1], 0, 0, 0); \
    acc[1][0] = __builtin_amdgcn_mfma_f32_32x32x16_bf16(av[1][ks], bv[0][ks], acc[1][0], 0, 0, 0); \
    acc[1][1] = __builtin_amdgcn_mfma_f32_32x32x16_bf16(av[1][ks], bv[1][ks], acc[1][1], 0, 0, 0);

#define KS_STEP(AVc, BVc, AVr, BVr, XC, c2_, Ar_, Br_, ks, DO_RD, DO_PREP)                   \
    if (DO_RD) { READ4(Ar_, Br_, AVr, BVr, ks) }                                            \
    if (DO_PREP) { BASIS_Q((c2_), ks, (XC)[ks]) }                                           \
    MFMA4(AVc, BVc, ks)                                                                      \
    if (DO_RD)   __builtin_amdgcn_sched_group_barrier(0x100, 4, 0);                          \
    if (DO_PREP) __builtin_amdgcn_sched_group_barrier(0x200, 1, 0);                          \
    __builtin_amdgcn_sched_group_barrier(0x008, 4, 0);

// tile kt: MFMA regs (AVc,BVc) [read last tile]; read frags(kt+1) from buf c1 -> (AVr,BVr);
// basis(kt+2) from XC -> Abuf c2; stage B(kt+2) -> Bbuf c2; reload XC's set with x(kt+4).
#define TILE(kt_, AVc, BVc, AVr, BVr, XC, XL, c1_, c2_, DO_RD, DO_PREP, DO_LX, DO_BAR) {     \
    if (DO_PREP) { STAGE_B2((c2_), ((kt_) + 2) * BK) }                                       \
    __builtin_amdgcn_sched_barrier(0);                                                       \
    const unsigned short* Ar_ = &sm[(c1_) * 16384];                                          \
    const unsigned short* Br_ = &sm[49152 + (c1_) * 8192];                                   \
    KS_STEP(AVc, BVc, AVr, BVr, XC, c2_, Ar_, Br_, 0, DO_RD, DO_PREP)                        \
    KS_STEP(AVc, BVc, AVr, BVr, XC, c2_, Ar_, Br_, 1, DO_RD, DO_PREP)                        \
    KS_STEP(AVc, BVc, AVr, BVr, XC, c2_, Ar_, Br_, 2, DO_RD, DO_PREP)                        \
    KS_STEP(AVc, BVc, AVr, BVr, XC, c2_, Ar_, Br_, 3, DO_RD, DO_PREP)                        \
    __builtin_amdgcn_sched_barrier(0);                                                       \
    if (DO_LX) { LOADX(XL, (kt_) + 4) }                                                      \
    if (DO_BAR) {                                                                            \
      if (DO_LX) { asm volatile("s_waitcnt vmcnt(4) lgkmcnt(0)" ::: "memory"); }             \
      else       { asm volatile("s_waitcnt vmcnt(0) lgkmcnt(0)" ::: "memory"); }             \
      __builtin_amdgcn_s_barrier();                                                          \
      __builtin_amdgcn_sched_barrier(0);                                                     \
    } }

  // ---- prologue: x(0..3), B(0),B(1) DMA, basis(0),(1), read frags(0) into set A
  float xrA[4], xrB[4];
  short8 avA[2][4], bvA[2][4], avB[2][4], bvB[2][4];
  LOADX(xrA, 0)
  LOADX(xrB, 1)
  STAGE_B2(0, 0)
  STAGE_B2(1, BK)
  asm volatile("s_waitcnt vmcnt(8)" ::: "memory");   // xrA done
  BASIS_Q(0, 0, xrA[0]) BASIS_Q(0, 1, xrA[1]) BASIS_Q(0, 2, xrA[2]) BASIS_Q(0, 3, xrA[3])
  LOADX(xrA, 2)
  asm volatile("s_waitcnt vmcnt(8)" ::: "memory");   // xrB done
  BASIS_Q(1, 0, xrB[0]) BASIS_Q(1, 1, xrB[1]) BASIS_Q(1, 2, xrB[2]) BASIS_Q(1, 3, xrB[3])
  LOADX(xrB, 3)
  asm volatile("s_waitcnt vmcnt(8) lgkmcnt(0)" ::: "memory");  // B(0),B(1) landed; basis done
  __builtin_amdgcn_s_barrier();
  {
    const unsigned short* Ar_ = &sm[0];
    const unsigned short* Br_ = &sm[49152];
    READ4(Ar_, Br_, avA, bvA, 0) READ4(Ar_, Br_, avA, bvA, 1)
    READ4(Ar_, Br_, avA, bvA, 2) READ4(Ar_, Br_, avA, bvA, 3)
  }

  // ---- main loop: tiles 0..123, all features on; buffers rotate +1 mod 3 per tile
  int r0 = 0, r1 = 1, r2 = 2;
  for (int kt = 0; kt < 124; kt += 2) {
    TILE(kt,     avA, bvA, avB, bvB, xrA, xrA, r1, r2, 1, 1, 1, 1)
    TILE(kt + 1, avB, bvB, avA, bvA, xrB, xrB, r2, r0, 1, 1, 1, 1)
    const int t_ = r0; r0 = r2; r2 = r1; r1 = t_;
  }
  // ---- peeled tail: 124 (no loadx), 125 (no loadx), 126 (reads only), 127 (MFMA only)
  TILE(124, avA, bvA, avB, bvB, xrA, xrA, 2, 0, 1, 1, 0, 1)
  TILE(125, avB, bvB, avA, bvA, xrB, xrB, 0, 1, 1, 1, 0, 1)
  TILE(126, avA, bvA, avB, bvB, xrA, xrA, 1, 2, 1, 0, 0, 1)
  TILE(127, avB, bvB, avA, bvA, xrB, xrB, 2, 0, 0, 0, 0, 0)
#undef TILE
#undef KS_STEP
#undef MFMA4
#undef READ4
#undef BASIS_Q
#undef LOADX
#undef STAGE_B2

  // epilogue: 32x32 C/D layout col = lane&31, row = (reg&3) + 8*(reg>>2) + 4*(lane>>5)
  #pragma unroll
  for (int ni = 0; ni < 2; ++ni) {
    const int col  = n0 + wn * 64 + ni * 32 + l31;
    const float bc = bias[col];
    #pragma unroll
    for (int mi = 0; mi < 2; ++mi) {
      const int rbase = m0 + wm * 64 + mi * 32 + 4 * half;
      #pragma unroll
      for (int r = 0; r < 16; ++r) {
        const int row = rbase + (r & 3) + 8 * (r >> 2);
        C[(size_t)row * N_DIM + col] = acc[mi][ni][r] + bc;
      }
    }
  }
}

extern "C" void kernel_launch(void* const* d_in, const int* in_sizes, int n_in,
                              void* d_out, int out_size, void* d_ws, size_t ws_size,
                              hipStream_t stream) {
  const float* x      = (const float*)d_in[0];
  const float* coeffs = (const float*)d_in[1];
  float* y            = (float*)d_out;

  const size_t bt_bytes = (size_t)N_DIM * K_DIM * sizeof(unsigned short); // 16.78 MB
  unsigned short* Bt = (unsigned short*)d_ws;
  float* bias        = (float*)((char*)d_ws + bt_bytes);

  // bias accumulator must start at zero (ws is poisoned 0xAA each call)
  hipMemsetAsync(bias, 0, N_DIM * sizeof(float), stream);

  // 144 KB dynamic LDS (triple-buffered A+B)
  hipFuncSetAttribute((const void*)gemm_kernel,
                      hipFuncAttributeMaxDynamicSharedMemorySize, 147456);

  repack_kernel<<<dim3(I_DIM / 32, N_DIM / 64), 256, 0, stream>>>(coeffs, Bt, bias);
  gemm_kernel<<<(B_ROWS / BM) * (N_DIM / BN), 512, 147456, stream>>>(x, Bt, bias, y);
}

// Round 11
// 262.897 us; speedup vs baseline: 1.0596x; 1.0456x over previous
//
#include <hip/hip_runtime.h>
#include <stdint.h>

#define B_ROWS 8192
#define I_DIM  1024
#define N_DIM  1024
#define NDEG   9                  // D+1 (d = 0..8)
#define K_DIM  (I_DIM * (NDEG-1)) // 8192; k = i*8 + (d-1), d = 1..8 (d=0 folded into bias)

#define BM 256
#define BN 128
#define BK 64
#define NT (K_DIM / BK)           // 128 K-tiles; tile kt covers i in [kt*8, kt*8+8)

typedef __attribute__((ext_vector_type(8)))  short short8;
typedef __attribute__((ext_vector_type(16))) float f32x16;

__device__ __forceinline__ unsigned short f2bf(float f) {
  union { float f; uint32_t u; } v; v.f = f;
  uint32_t u = v.u;
  u += 0x7FFFu + ((u >> 16) & 1u);   // round-to-nearest-even
  return (unsigned short)(u >> 16);
}

__device__ __forceinline__ float bf2f(unsigned short h) {
  union { uint32_t u; float f; } v; v.u = ((uint32_t)h) << 16;
  return v.f;
}

// packed f32->bf16 (RTNE), 1 instr for 2 values; no builtin on gfx950, asm only
__device__ __forceinline__ uint32_t pk_bf16(float lo, float hi) {
  uint32_t r;
  asm("v_cvt_pk_bf16_f32 %0, %1, %2" : "=v"(r) : "v"(lo), "v"(hi));
  return r;
}

// fast tanh: 1 - 2/(e^{2x}+1); exact limits at +-inf, err ~1e-7 << bf16 quantization
__device__ __forceinline__ float fast_tanh(float x) {
  float e = __expf(2.0f * x);
  return 1.0f - __fdividef(2.0f, e + 1.0f);
}

__device__ __forceinline__ int h2(int r) { return (r >> 2) & 7; }

// ---------------- repack: C[i,o,d] fp32 -> Bt[o, i*8+(d-1)] bf16 (d>=1); bias[o] += sum_i C[i,o,0]
__global__ __launch_bounds__(256) void repack_kernel(const float* __restrict__ cf,
                                                     unsigned short* __restrict__ Bt,
                                                     float* __restrict__ bias) {
  __shared__ unsigned short L[32][584];   // [i_local][o_local*9+d], padded
  const int i0  = blockIdx.x * 32;
  const int o0  = blockIdx.y * 64;
  const int tid = threadIdx.x;

  #pragma unroll
  for (int j = 0; j < 18; ++j) {               // 18*256 = 4608 float4 = 32*576 floats
    const int f4  = j * 256 + tid;
    const int il  = f4 / 144;
    const int odq = f4 % 144;
    const float4 v = *reinterpret_cast<const float4*>(
        cf + ((size_t)(i0 + il) * N_DIM + o0) * NDEG + (size_t)odq * 4);
    ushort4 w;
    w.x = f2bf(v.x); w.y = f2bf(v.y); w.z = f2bf(v.z); w.w = f2bf(v.w);
    *reinterpret_cast<ushort4*>(&L[il][odq * 4]) = w;
  }
  __syncthreads();

  // one (o, i-octet) unit per thread: 64 consecutive shorts = 8 i x 8 d
  const int o  = tid >> 2;        // 0..63
  const int ci = tid & 3;         // 0..3
  const size_t base = (size_t)(o0 + o) * K_DIM + (size_t)(i0 + ci * 8) * 8;
  #pragma unroll
  for (int p = 0; p < 8; ++p) {   // i = i0 + ci*8 + p; shorts [d-1 = 0..7]
    const int il = ci * 8 + p;
    uint4 u;
    u.x = (uint32_t)L[il][o*9 + 1] | ((uint32_t)L[il][o*9 + 2] << 16);
    u.y = (uint32_t)L[il][o*9 + 3] | ((uint32_t)L[il][o*9 + 4] << 16);
    u.z = (uint32_t)L[il][o*9 + 5] | ((uint32_t)L[il][o*9 + 6] << 16);
    u.w = (uint32_t)L[il][o*9 + 7] | ((uint32_t)L[il][o*9 + 8] << 16);
    *reinterpret_cast<uint4*>(Bt + base + (size_t)p * 8) = u;
  }
  if (tid < 64) {
    float s = 0.f;
    #pragma unroll
    for (int il = 0; il < 32; ++il) s += bf2f(L[il][tid * 9]);
    atomicAdd(&bias[o0 + tid], s);
  }
}

// ---------------- fused basis+GEMM, pair-rotated read pipeline over triple-buffered LDS ---
// Same as R10 with ONE fix: LOADX is issued AFTER the ks-steps (R9's position). R10 put it
// at the tile top, overwriting xrE/xrO (x for kt+2) with x(kt+4) BEFORE BASIS_Q consumed
// it -> wrong basis everywhere (absmax 4.9e-2). Pipeline recap: av/bv[2][4] slots rotate
// as a pair pipeline over a TRIPLE-buffered LDS (144 KB):
//   step0: READ slot2 <- buf[kt]   | basis q0 -> buf[kt+2] | MFMA slot0 (read last tile)
//   step1: READ slot3 <- buf[kt]   | basis q1              | MFMA slot1 (read last tile)
//   step2: READ slot0 <- buf[kt+1] | basis q2              | MFMA slot2 (read at step0)
//   step3: READ slot1 <- buf[kt+1] | basis q3              | MFMA slot3 (read at step1)
// Every MFMA is >=2 sched-steps behind its ds_read; reads flow across the barrier.
// One barrier/tile, uniform vmcnt(4): queue = [x(kt-1)x4, stage(kt)x2, x(kt)x4] ->
// drains old x + this tile's B-stages (certified for kt+2), keeps 4 new x in flight.
__global__ __launch_bounds__(512, 2) void gemm_kernel(const float* __restrict__ x,
                                                      const unsigned short* __restrict__ Bt,
                                                      const float* __restrict__ bias,
                                                      float* __restrict__ C) {
  extern __shared__ unsigned short sm[];   // A: 3x16384 shorts @0 ; B: 3x8192 @49152
  const int tid  = threadIdx.x;
  const int lane = tid & 63;
  const int wave = tid >> 6;        // 0..7
  const int l31  = lane & 31;
  const int half = lane >> 5;       // 0..1 -> k-offset 8*half
  const int wm   = wave >> 1;       // 0..3
  const int wn   = wave & 1;        // 0..1

  // bijective XCD swizzle: all 8 n-blocks of one m-tile share bid%8 -> same XCD L2 (x reuse)
  const int bid = blockIdx.x;
  const int mt  = (bid & 7) + 8 * (bid >> 6);
  const int nt  = (bid >> 3) & 7;
  const int m0  = mt * BM;
  const int n0  = nt * BN;

  const int sr   = tid >> 3;        // 0..63: staging row / basis row-quarter
  const int slot = tid & 7;         // 16B chunk slot (staging) / basis i_loc

  const unsigned short* Bbase = Bt + (size_t)n0 * K_DIM;

  // hoisted basis constants: LDS write offsets (shorts, within an A-buffer) + x pointers
  int awoff[4];
  const float* xptr[4];
  #pragma unroll
  for (int q = 0; q < 4; ++q) {
    const int r_ = q * 64 + sr;
    awoff[q] = r_ * 64 + (slot ^ h2(r_)) * 8;
    xptr[q]  = x + (size_t)(m0 + r_) * I_DIM + slot;
  }

  f32x16 acc[2][2];
  #pragma unroll
  for (int a = 0; a < 2; ++a)
    #pragma unroll
    for (int b = 0; b < 2; ++b)
      #pragma unroll
      for (int r = 0; r < 16; ++r)
        acc[a][b][r] = 0.f;

#define STAGE_B2(bf, kk) {                                                                  \
    _Pragma("unroll")                                                                       \
    for (int s_ = 0; s_ < 2; ++s_) {                                                        \
      const int r_ = s_ * 64 + sr; const int gc_ = slot ^ h2(r_);                           \
      __builtin_amdgcn_global_load_lds(                                                     \
        (const __attribute__((address_space(1))) void*)(Bbase + (size_t)r_*K_DIM + (kk) + gc_*8), \
        (__attribute__((address_space(3))) void*)&sm[49152 + (bf)*8192 + r_*64 + slot*8], 16, 0, 0); \
    } }

#define LOADX(xr, tt) {                                                                     \
    _Pragma("unroll")                                                                       \
    for (int q = 0; q < 4; ++q) xr[q] = xptr[q][(tt) * 8]; }

// one basis quarter: row q*64+sr, value = T_1..T_8(clamp(tanh(xv))) -> 16B LDS write
#define BASIS_Q(bf, q, xv) {                                                                \
      float t = fast_tanh(xv);                                                              \
      t = fminf(fmaxf(t, -0.999f), 0.999f);                                                 \
      const float t2 = t + t;                                                               \
      const float T1 = t;                                                                   \
      const float T2 = t2*t - 1.0f;                                                         \
      const float T3 = t2*T2 - T1;                                                          \
      const float T4 = t2*T3 - T2;                                                          \
      const float T5 = t2*T4 - T3;                                                          \
      const float T6 = t2*T5 - T4;                                                          \
      const float T7 = t2*T6 - T5;                                                          \
      const float T8 = t2*T7 - T6;                                                          \
      uint4 u;                                                                              \
      u.x = pk_bf16(T1, T2); u.y = pk_bf16(T3, T4);                                         \
      u.z = pk_bf16(T5, T6); u.w = pk_bf16(T7, T8);                                         \
      *reinterpret_cast<uint4*>(&sm[(bf)*16384 + awoff[q]]) = u; }

  const int rowA0 = wm * 64 + l31;
  const int rowA1 = wm * 64 + 32 + l31;
  const int rowB0 = wn * 64 + l31;
  const int rowB1 = wn * 64 + 32 + l31;
  const int hA0 = h2(rowA0), hA1 = h2(rowA1), hB0 = h2(rowB0), hB1 = h2(rowB1);

  short8 av[2][4], bv[2][4];   // ks-slot-rotating fragment registers (persist across tiles)

#define READ4(Ar, Br, ks) {                                                                  \
    const int c_ = (ks) * 2 + half;                                                          \
    av[0][ks] = *reinterpret_cast<const short8*>(&(Ar)[rowA0 * 64 + (c_ ^ hA0) * 8]);        \
    av[1][ks] = *reinterpret_cast<const short8*>(&(Ar)[rowA1 * 64 + (c_ ^ hA1) * 8]);        \
    bv[0][ks] = *reinterpret_cast<const short8*>(&(Br)[rowB0 * 64 + (c_ ^ hB0) * 8]);        \
    bv[1][ks] = *reinterpret_cast<const short8*>(&(Br)[rowB1 * 64 + (c_ ^ hB1) * 8]); }

#define MFMA4(ks)                                                                            \
    acc[0][0] = __builtin_amdgcn_mfma_f32_32x32x16_bf16(av[0][ks], bv[0][ks], acc[0][0], 0, 0, 0); \
    acc[0][1] = __builtin_amdgcn_mfma_f32_32x32x16_bf16(av[0][ks], bv[1][ks], acc[0][1], 0, 0, 0); \
    acc[1][0] = __builtin_amdgcn_mfma_f32_32x32x16_bf16(av[1][ks], bv[0][ks], acc[1][0], 0, 0, 0); \
    acc[1][1] = __builtin_amdgcn_mfma_f32_32x32x16_bf16(av[1][ks], bv[1][ks], acc[1][1], 0, 0, 0);

#define PINS(PREP) \
    __builtin_amdgcn_sched_group_barrier(0x100, 4, 0);                                       \
    if (PREP) __builtin_amdgcn_sched_group_barrier(0x200, 1, 0);                             \
    __builtin_amdgcn_sched_group_barrier(0x008, 4, 0);

// tile kk: cur buf c0, next buf c1 (read slots 0,1 for tile kk+1), target buf c2
// (basis+stage for kk+2). LOADX placed AFTER the ks-steps: XC's old values (x(kk+2))
// are consumed by BASIS_Q first, then reloaded with x(kk+4). BARV: vmcnt at barrier.
#define TILE(kk, c0, c1, c2, XC, PREP, LX, BARV) {                                           \
    if (PREP) { STAGE_B2(c2, ((kk) + 2) * BK) }                                              \
    __builtin_amdgcn_sched_barrier(0);                                                       \
    const unsigned short* Ac_ = &sm[(c0) * 16384];                                           \
    const unsigned short* Bc_ = &sm[49152 + (c0) * 8192];                                    \
    const unsigned short* An_ = &sm[(c1) * 16384];                                           \
    const unsigned short* Bn_ = &sm[49152 + (c1) * 8192];                                    \
    READ4(Ac_, Bc_, 2) if (PREP) { BASIS_Q(c2, 0, (XC)[0]) } MFMA4(0)                        \
    PINS(PREP)                                                                               \
    READ4(Ac_, Bc_, 3) if (PREP) { BASIS_Q(c2, 1, (XC)[1]) } MFMA4(1)                        \
    PINS(PREP)                                                                               \
    READ4(An_, Bn_, 0) if (PREP) { BASIS_Q(c2, 2, (XC)[2]) } MFMA4(2)                        \
    PINS(PREP)                                                                               \
    READ4(An_, Bn_, 1) if (PREP) { BASIS_Q(c2, 3, (XC)[3]) } MFMA4(3)                        \
    PINS(PREP)                                                                               \
    __builtin_amdgcn_sched_barrier(0);                                                       \
    if (LX) { LOADX(XC, (kk) + 4) }                                                          \
    __builtin_amdgcn_sched_barrier(0);                                                       \
    asm volatile("s_waitcnt vmcnt(" #BARV ") lgkmcnt(0)" ::: "memory");                      \
    __builtin_amdgcn_s_barrier();                                                            \
    __builtin_amdgcn_sched_barrier(0); }

  // ---- prologue: x(0..3), B(0),B(1) DMA, basis(0)->buf0, basis(1)->buf1, frags slot0,1
  float xrE[4], xrO[4];
  LOADX(xrE, 0)
  LOADX(xrO, 1)
  STAGE_B2(0, 0)
  STAGE_B2(1, BK)
  asm volatile("s_waitcnt vmcnt(8)" ::: "memory");   // xrE (x0) done
  BASIS_Q(0, 0, xrE[0]) BASIS_Q(0, 1, xrE[1]) BASIS_Q(0, 2, xrE[2]) BASIS_Q(0, 3, xrE[3])
  LOADX(xrE, 2)
  asm volatile("s_waitcnt vmcnt(8)" ::: "memory");   // xrO (x1) done
  BASIS_Q(1, 0, xrO[0]) BASIS_Q(1, 1, xrO[1]) BASIS_Q(1, 2, xrO[2]) BASIS_Q(1, 3, xrO[3])
  LOADX(xrO, 3)
  asm volatile("s_waitcnt vmcnt(8) lgkmcnt(0)" ::: "memory"); // B stages landed; basis done
  __builtin_amdgcn_s_barrier();
  {
    const unsigned short* Ar_ = &sm[0];
    const unsigned short* Br_ = &sm[49152];
    READ4(Ar_, Br_, 0) READ4(Ar_, Br_, 1)
  }

  // ---- main loop: tiles 0..119 (unroll x6 = lcm of buffer mod-3 and x parity mod-2)
  for (int kt = 0; kt < 120; kt += 6) {
    TILE(kt + 0, 0, 1, 2, xrE, 1, 1, 4)
    TILE(kt + 1, 1, 2, 0, xrO, 1, 1, 4)
    TILE(kt + 2, 2, 0, 1, xrE, 1, 1, 4)
    TILE(kt + 3, 0, 1, 2, xrO, 1, 1, 4)
    TILE(kt + 4, 1, 2, 0, xrE, 1, 1, 4)
    TILE(kt + 5, 2, 0, 1, xrO, 1, 1, 4)
  }
  // ---- peeled tail (x loads stop after kt=123: x(127) is the last octet)
  TILE(120, 0, 1, 2, xrE, 1, 1, 4)
  TILE(121, 1, 2, 0, xrO, 1, 1, 4)
  TILE(122, 2, 0, 1, xrE, 1, 1, 4)   // consumes x(124); loads x(126) into xrE
  TILE(123, 0, 1, 2, xrO, 1, 1, 4)   // consumes x(125); loads x(127) into xrO
  TILE(124, 1, 2, 0, xrE, 1, 0, 0)   // basis(126); no more x
  TILE(125, 2, 0, 1, xrO, 1, 0, 0)   // basis(127)
  TILE(126, 0, 1, 2, xrE, 0, 0, 0)   // reads only (slots 0,1 <- buf[127]=buf1)
  { // tile 127 (cur buf 1): reads slots 2,3; 16 MFMA; no barrier
    const unsigned short* Ac_ = &sm[16384];
    const unsigned short* Bc_ = &sm[49152 + 8192];
    READ4(Ac_, Bc_, 2) MFMA4(0)
    __builtin_amdgcn_sched_group_barrier(0x100, 4, 0);
    __builtin_amdgcn_sched_group_barrier(0x008, 4, 0);
    READ4(Ac_, Bc_, 3) MFMA4(1)
    __builtin_amdgcn_sched_group_barrier(0x100, 4, 0);
    __builtin_amdgcn_sched_group_barrier(0x008, 4, 0);
    MFMA4(2)
    __builtin_amdgcn_sched_group_barrier(0x008, 4, 0);
    MFMA4(3)
    __builtin_amdgcn_sched_group_barrier(0x008, 4, 0);
  }
#undef TILE
#undef PINS
#undef MFMA4
#undef READ4
#undef BASIS_Q
#undef LOADX
#undef STAGE_B2

  // epilogue: 32x32 C/D layout col = lane&31, row = (reg&3) + 8*(reg>>2) + 4*(lane>>5)
  #pragma unroll
  for (int ni = 0; ni < 2; ++ni) {
    const int col  = n0 + wn * 64 + ni * 32 + l31;
    const float bc = bias[col];
    #pragma unroll
    for (int mi = 0; mi < 2; ++mi) {
      const int rbase = m0 + wm * 64 + mi * 32 + 4 * half;
      #pragma unroll
      for (int r = 0; r < 16; ++r) {
        const int row = rbase + (r & 3) + 8 * (r >> 2);
        C[(size_t)row * N_DIM + col] = acc[mi][ni][r] + bc;
      }
    }
  }
}

extern "C" void kernel_launch(void* const* d_in, const int* in_sizes, int n_in,
                              void* d_out, int out_size, void* d_ws, size_t ws_size,
                              hipStream_t stream) {
  const float* x      = (const float*)d_in[0];
  const float* coeffs = (const float*)d_in[1];
  float* y            = (float*)d_out;

  const size_t bt_bytes = (size_t)N_DIM * K_DIM * sizeof(unsigned short); // 16.78 MB
  unsigned short* Bt = (unsigned short*)d_ws;
  float* bias        = (float*)((char*)d_ws + bt_bytes);

  // bias accumulator must start at zero (ws is poisoned 0xAA each call)
  hipMemsetAsync(bias, 0, N_DIM * sizeof(float), stream);

  // 144 KB dynamic LDS (triple-buffered A+B)
  hipFuncSetAttribute((const void*)gemm_kernel,
                      hipFuncAttributeMaxDynamicSharedMemorySize, 147456);

  repack_kernel<<<dim3(I_DIM / 32, N_DIM / 64), 256, 0, stream>>>(coeffs, Bt, bias);
  gemm_kernel<<<(B_ROWS / BM) * (N_DIM / BN), 512, 147456, stream>>>(x, Bt, bias, y);
}